// Round 12
// baseline (612.528 us; speedup 1.0000x reference)
//
#include <hip/hip_runtime.h>
#include <cmath>

// MuSeGNN on MI355X — round 16: comb-GEMM residency fix (grid was the
// occupancy limiter).
//
// r15: exact r13 restore confirmed at 599.5us (repro <1us). Audit: deg ~
// Poisson(32) -> no node exceeds 64 edges -> attn is single-chunk for every
// node (this is WHY bit-exactness vs JAX holds); 32-edge restructures would
// break it for ~47% of nodes. Attn parked (latency-bound, LDS floor 33.3KB
// caps 4 blocks/CU). Remaining: 6 GEMM dispatches ~40us each vs ~15us
// intrinsic -> comb grid (313,2)=626 blocks = 2.4/CU is the limiter (LDS/
// VGPR would allow 8). Single change: comb <32,64,2,4> -> <16,64,1,4>,
// grid (625,2)=1250 = 4.9/CU, LDS 11.2KB, As read = 16-lane broadcast.
// Ascending-k chain + epilogue identical -> bit-exact.
// Pre-commit: null -> comb not grid-limited (ugemm next); regress -> revert.
//
// Algebra (verified r1-r15, absmax 0.0): alpha_e = u[dst]·h[src] (+softmax-
// invariant const; bk drops), u = h·(Wq_h Wk_h^T/√C) + bq·Wk_h^T/√C.
// out[dst] = mean_h((Σ_e a_e h[src])·Wv_h + bv_h) + h@Wskip + bskip; deg=0
// rows lose the attention term AND bv (empty segment sum).

#define NN    10000
#define NTOT  80000
#define EE    320000
#define CH    128

__device__ __forceinline__ float rl_f(float v, int lane) {
    return __uint_as_float(__builtin_amdgcn_readlane(__float_as_uint(v), lane));
}

// ---------------------------------------------------------------------------
// Precompute: Bcat (128x640 = [Pm | Wskip]), biascat (640 = [r | bskip]),
// Wcomb (512x128 = Wv/4 stacked (h,c)-major), bvbar, BN scale/bias.
// ---------------------------------------------------------------------------
__global__ __launch_bounds__(256) void precompute_kernel(
    const float* __restrict__ Wq, const float* __restrict__ bq,
    const float* __restrict__ Wk, const float* __restrict__ Wv,
    const float* __restrict__ bv, const float* __restrict__ Wskip,
    const float* __restrict__ bskip,
    const float* __restrict__ bn_gamma, const float* __restrict__ bn_beta,
    const float* __restrict__ bn_mean, const float* __restrict__ bn_var,
    float* __restrict__ Bcat, float* __restrict__ biascat,
    float* __restrict__ Wcomb, float* __restrict__ bvbar,
    float* __restrict__ bnS, float* __restrict__ bnB)
{
    const float inv_sqrtC = 0.08838834764831845f;  // 1/sqrt(128)
    int idx = blockIdx.x * 256 + threadIdx.x;
    if (idx < 65536) {            // Pm part: Bcat[c, o] o<512
        int c = idx >> 9;
        int o = idx & 511;
        int hbase = o & ~127;
        int j = o & 127;
        const float* wq = Wq + c * 512 + hbase;
        const float* wk = Wk + j * 512 + hbase;
        float s = 0.f;
        for (int cc = 0; cc < 128; cc++) s = fmaf(wq[cc], wk[cc], s);
        Bcat[c * 640 + o] = s * inv_sqrtC;
        return;
    }
    idx -= 65536;
    if (idx < 16384) {            // Wskip part: Bcat[c, 512+n]
        int c = idx >> 7, n = idx & 127;
        Bcat[c * 640 + 512 + n] = Wskip[c * 128 + n];
        return;
    }
    idx -= 16384;
    if (idx < 512) {              // biascat[0..511] = r
        int o = idx, hbase = o & ~127, j = o & 127;
        const float* wk = Wk + j * 512 + hbase;
        const float* bqp = bq + hbase;
        float s = 0.f;
        for (int cc = 0; cc < 128; cc++) s = fmaf(bqp[cc], wk[cc], s);
        biascat[o] = s * inv_sqrtC;
        return;
    }
    idx -= 512;
    if (idx < 128) {              // biascat[512..639] = bskip
        biascat[512 + idx] = bskip[idx];
        return;
    }
    idx -= 128;
    if (idx < 65536) {            // Wcomb[k, n], k=(h,c): Wv[c, h*128+n] / 4
        int k = idx >> 7;
        int n = idx & 127;
        int h = k >> 7, c = k & 127;
        Wcomb[k * 128 + n] = Wv[c * 512 + h * 128 + n] * 0.25f;
        return;
    }
    idx -= 65536;
    if (idx < 128) {              // bvbar = mean over heads of bv
        float s = 0.f;
        for (int h = 0; h < 4; h++) s += bv[h * 128 + idx];
        bvbar[idx] = 0.25f * s;
        return;
    }
    idx -= 128;
    if (idx < 384) {              // BN fold (eval): y = x*scale + bias
        float sc = bn_gamma[idx] / sqrtf(bn_var[idx] + 1e-5f);
        bnS[idx] = sc;
        bnB[idx] = bn_beta[idx] - bn_mean[idx] * sc;
        return;
    }
}

// ---------------------------------------------------------------------------
// CSR build by dst
// ---------------------------------------------------------------------------
__global__ void count_kernel(const int* __restrict__ dst, int* __restrict__ deg) {
    int e = blockIdx.x * 256 + threadIdx.x;
    if (e < EE) atomicAdd(&deg[dst[e]], 1);
}

__global__ __launch_bounds__(1024) void scan_kernel(const int* __restrict__ deg,
                                                    int* __restrict__ rowstart) {
    __shared__ int part[1024];
    const int t = threadIdx.x;
    int loc[10];
    int s = 0;
    for (int i = 0; i < 10; i++) {
        int idx = t * 10 + i;
        int v = (idx < NN) ? deg[idx] : 0;
        loc[i] = s; s += v;
    }
    part[t] = s; __syncthreads();
    for (int d = 1; d < 1024; d <<= 1) {
        int v = (t >= d) ? part[t - d] : 0;
        __syncthreads();
        part[t] += v;
        __syncthreads();
    }
    int base = (t == 0) ? 0 : part[t - 1];
    for (int i = 0; i < 10; i++) {
        int idx = t * 10 + i;
        if (idx <= NN) rowstart[idx] = base + loc[i];
    }
}

__global__ void scatter_kernel(const int* __restrict__ src, const int* __restrict__ dst,
                               const int* __restrict__ rowstart, int* __restrict__ cursor,
                               int* __restrict__ csr_src) {
    int e = blockIdx.x * 256 + threadIdx.x;
    if (e < EE) {
        int d = dst[e];
        int p = atomicAdd(&cursor[d], 1);
        csr_src[rowstart[d] + p] = src[e];
    }
}

// ---------------------------------------------------------------------------
// Upper rows (>= NN): layers 1-2 (lane->row, SGPR-B) + layer-3 key (col 127).
// (r13 version: 512 threads / 8 waves / 16 cols per wave — measured 76.5us.)
// ---------------------------------------------------------------------------
__global__ __launch_bounds__(512, 4) void skip_keys_kernel(
    const float* __restrict__ xup,    // (NTOT-NN) x 128
    const float* __restrict__ Wskip,  // 128 x 128
    const float* __restrict__ bskip,
    const float* __restrict__ bnS, const float* __restrict__ bnB,  // [3][128]
    float* __restrict__ gkeys)        // NTOT keys; this writes [NN, NTOT)
{
    __shared__ float rowb[64][132];
    __shared__ float sWc[128];
    const int t = threadIdx.x;
    const int l = t & 63;                                    // row
    const int wv = __builtin_amdgcn_readfirstlane(t >> 6);   // 0..7, wave-uniform
    const int colbase = wv * 16;
    const int r0 = blockIdx.x * 64;
    const int Mrem = min(64, (NTOT - NN) - r0);

    for (int f = t; f < 64 * 32; f += 512) {
        int row = f >> 5, c4 = (f & 31) * 4;
        float4 v = make_float4(0.f, 0.f, 0.f, 0.f);
        if (row < Mrem) v = *(const float4*)(xup + (size_t)(r0 + row) * CH + c4);
        *(float4*)&rowb[row][c4] = v;
    }
    if (t < 128) sWc[t] = Wskip[t * 128 + 127];
    __syncthreads();

    for (int layer = 0; layer < 2; layer++) {
        float acc[16];
        #pragma unroll
        for (int c = 0; c < 16; c++) acc[c] = 0.f;
        const float* Wb = Wskip + colbase;
        for (int kq = 0; kq < 32; kq++) {
            const float4 a4 = *(const float4*)&rowb[l][kq * 4];
            #pragma unroll
            for (int q = 0; q < 4; q++) {
                const float av = (q == 0) ? a4.x : (q == 1) ? a4.y
                               : (q == 2) ? a4.z : a4.w;
                const float* wr = Wb + (kq * 4 + q) * 128;
                #pragma unroll
                for (int c = 0; c < 16; c++)
                    acc[c] = fmaf(av, wr[c], acc[c]);
            }
        }
        __syncthreads();           // all rowb reads done before overwrite
        const float* bS = bnS + layer * 128;
        const float* bB = bnB + layer * 128;
        #pragma unroll
        for (int c4 = 0; c4 < 4; c4++) {
            float4 v;
            float* vp = &v.x;
            #pragma unroll
            for (int q = 0; q < 4; q++) {
                const int n = colbase + c4 * 4 + q;
                float xv = acc[c4 * 4 + q] + bskip[n];
                xv = fmaf(xv, bS[n], bB[n]);
                vp[q] = fmaxf(xv, 0.f);
            }
            *(float4*)&rowb[l][colbase + c4 * 4] = v;
        }
        __syncthreads();
    }
    // layer-3 key only: col 127, sequential-k fmaf (bit-identical chain).
    if (t < Mrem) {
        float s = 0.f;
        for (int k = 0; k < 128; k++) s = fmaf(rowb[t][k], sWc[k], s);
        s += bskip[127];
        s = fmaf(s, bnS[2 * 128 + 127], bnB[2 * 128 + 127]);
        gkeys[NN + r0 + t] = fmaxf(s, 0.f);
    }
}

// ---------------------------------------------------------------------------
// fp32 tiled GEMM, 256 threads, BK template — BK=32 in use. TM in {1,2,4}.
// MODE 0 (ug): C = A*B + bias, dual dest: cols <512 -> C0 (u), >=512 -> C1.
// MODE 4 (comb'): C0 = relu(bn(A*B + Cold + (deg>0)*bias2)); optionally
//              mirrors col 127 into keysOut (for the final layer).
// ---------------------------------------------------------------------------
template<int BM, int BN, int TM, int TN, int MODE, int BK>
__global__ __launch_bounds__(256) void gemm_fp32(
    const float* __restrict__ A, int lda,
    const float* __restrict__ B, int ldb,
    const float* __restrict__ bias, const float* __restrict__ bias2,
    const int* __restrict__ deg,
    const float* __restrict__ Cold,
    const float* __restrict__ bnS, const float* __restrict__ bnB,
    float* __restrict__ C0, int ldc0,
    float* __restrict__ C1, int ldc1,
    int M, int K,
    float* __restrict__ keysOut)
{
    constexpr int KF = BK / 4;           // float4s per row per k-tile
    __shared__ float As[BK][BM + 4];
    __shared__ float Bs[BK][BN + 4];
    const int t  = threadIdx.x;
    const int tx = t % (BN / TN);
    const int ty = t / (BN / TN);
    const int m0 = blockIdx.x * BM;
    const int n0 = blockIdx.y * BN;
    float acc[TM][TN];
    #pragma unroll
    for (int i = 0; i < TM; i++)
        #pragma unroll
        for (int j = 0; j < TN; j++) acc[i][j] = 0.f;

    for (int k0 = 0; k0 < K; k0 += BK) {
        #pragma unroll
        for (int f = t; f < BM * KF; f += 256) {
            int row = f / KF, fc = f % KF;
            int gm = m0 + row;
            float4 v = make_float4(0.f, 0.f, 0.f, 0.f);
            if (gm < M) v = *(const float4*)(A + (size_t)gm * lda + k0 + fc * 4);
            As[fc * 4 + 0][row] = v.x;
            As[fc * 4 + 1][row] = v.y;
            As[fc * 4 + 2][row] = v.z;
            As[fc * 4 + 3][row] = v.w;
        }
        #pragma unroll
        for (int f = t; f < BK * (BN / 4); f += 256) {
            int kk = f / (BN / 4);
            int nn = (f % (BN / 4)) * 4;
            *(float4*)(&Bs[kk][nn]) = *(const float4*)(B + (size_t)(k0 + kk) * ldb + n0 + nn);
        }
        __syncthreads();
        #pragma unroll
        for (int kk = 0; kk < BK; kk++) {
            float af[TM], bf[TN];
            if constexpr (TM == 1) {
                af[0] = As[kk][ty];
            } else if constexpr (TM == 2) {
                float2 v = *(const float2*)&As[kk][ty * 2];
                af[0] = v.x; af[1] = v.y;
            } else {  // TM == 4
                float4 v = *(const float4*)&As[kk][ty * 4];
                af[0] = v.x; af[1] = v.y; af[2] = v.z; af[3] = v.w;
            }
            if constexpr (TN == 4) {
                float4 v = *(const float4*)&Bs[kk][tx * 4];
                bf[0] = v.x; bf[1] = v.y; bf[2] = v.z; bf[3] = v.w;
            } else {  // TN == 8: split cols
                float4 v = *(const float4*)&Bs[kk][tx * 4];
                float4 w = *(const float4*)&Bs[kk][BN / 2 + tx * 4];
                bf[0] = v.x; bf[1] = v.y; bf[2] = v.z; bf[3] = v.w;
                bf[4] = w.x; bf[5] = w.y; bf[6] = w.z; bf[7] = w.w;
            }
            #pragma unroll
            for (int i = 0; i < TM; i++)
                #pragma unroll
                for (int j = 0; j < TN; j++)
                    acc[i][j] = fmaf(af[i], bf[j], acc[i][j]);
        }
        __syncthreads();
    }
    // epilogue
    #pragma unroll
    for (int i = 0; i < TM; i++) {
        const int gm = m0 + ty * TM + i;
        if (gm >= M) continue;
        const bool addB2 = (MODE == 4) ? (deg[gm] > 0) : false;
        #pragma unroll
        for (int h = 0; h < TN / 4; h++) {
            const int nb = n0 + ((TN == 8) ? h * (BN / 2) + tx * 4 : tx * TN + h * 4);
            float4 v;
            float* vp = &v.x;
            if (MODE == 4) {
                const float4 old = *(const float4*)(Cold + (size_t)gm * ldc1 + nb);
                const float* op = &old.x;
                #pragma unroll
                for (int q = 0; q < 4; q++) {
                    const int n = nb + q;
                    float x = acc[i][h * 4 + q] + op[q];
                    if (addB2) x += bias2[n];
                    x = fmaf(x, bnS[n], bnB[n]);
                    vp[q] = fmaxf(x, 0.f);
                }
                *(float4*)(C0 + (size_t)gm * ldc0 + nb) = v;
                if (keysOut != nullptr && nb == 124) keysOut[gm] = v.w;  // col 127
            } else {
                #pragma unroll
                for (int q = 0; q < 4; q++)
                    vp[q] = acc[i][h * 4 + q] + bias[nb + q];
                if (nb < 512)
                    *(float4*)(C0 + (size_t)gm * ldc0 + nb) = v;
                else
                    *(float4*)(C1 + (size_t)gm * ldc1 + nb - 512) = v;
            }
        }
    }
}

// ---------------------------------------------------------------------------
// Attention: one block per dst node, chunked online softmax over CSR edges.
// (r13 version: src_lds staging; merge aliased onto h_lds -> 4 blocks/CU.)
// ---------------------------------------------------------------------------
__global__ __launch_bounds__(256) void attn_kernel(
    const float* __restrict__ h,
    const float* __restrict__ u,
    float* __restrict__ g,
    const int* __restrict__ rowstart,
    const int* __restrict__ csr_src)
{
    __shared__ __align__(16) float h_lds[128 * 65];
    __shared__ __align__(16) float palpha[4 * 64 * 4];   // [ht][j][w]
    __shared__ __align__(16) float wT[64 * 4];           // [j][ht]
    __shared__ __align__(16) float scale_lds[4];
    __shared__ __align__(16) float s_lds[4];
    __shared__ int src_lds[64];
    float* merge = h_lds;       // aliased: only live after the chunk loop

    const int n  = blockIdx.x;
    const int t  = threadIdx.x;
    const int w  = t >> 6;      // wave id
    const int l  = t & 63;      // lane
    const int c  = t & 127;     // acc channel
    const int jh = t >> 7;      // acc j-half
    const int rs   = rowstart[n];
    const int degn = rowstart[n + 1] - rs;

    if (degn == 0) {
        g[(size_t)n * 512 + t] = 0.f;
        g[(size_t)n * 512 + 256 + t] = 0.f;
        return;
    }
    float u_reg0 = u[(size_t)n * 512 + ((l >> 5)) * 128 + 32 * w + (l & 31)];
    float u_reg1 = u[(size_t)n * 512 + ((l >> 5) + 2) * 128 + 32 * w + (l & 31)];

    float m_run = -INFINITY, s_run = 0.f;
    float4 acc4 = make_float4(0.f, 0.f, 0.f, 0.f);

    for (int base = 0; base < degn; base += 64) {
        const int len = min(64, degn - base);
        __syncthreads();
        if (t < len) src_lds[t] = csr_src[rs + base + t];
        __syncthreads();
        for (int f = t; f < len * 32; f += 256) {
            const int j = f >> 5, c4 = (f & 31) * 4;
            const float4 v = *(const float4*)(h + (size_t)src_lds[j] * CH + c4);
            h_lds[(c4 + 0) * 65 + j] = v.x;
            h_lds[(c4 + 1) * 65 + j] = v.y;
            h_lds[(c4 + 2) * 65 + j] = v.z;
            h_lds[(c4 + 3) * 65 + j] = v.w;
        }
        __syncthreads();
        {
            float p0 = 0.f, p1 = 0.f, p2 = 0.f, p3 = 0.f;
            #pragma unroll
            for (int dc = 0; dc < 32; dc++) {
                const float hv = h_lds[(32 * w + dc) * 65 + l];
                p0 = fmaf(rl_f(u_reg0, dc),      hv, p0);
                p1 = fmaf(rl_f(u_reg0, 32 + dc), hv, p1);
                p2 = fmaf(rl_f(u_reg1, dc),      hv, p2);
                p3 = fmaf(rl_f(u_reg1, 32 + dc), hv, p3);
            }
            palpha[(0 * 64 + l) * 4 + w] = p0;
            palpha[(1 * 64 + l) * 4 + w] = p1;
            palpha[(2 * 64 + l) * 4 + w] = p2;
            palpha[(3 * 64 + l) * 4 + w] = p3;
        }
        __syncthreads();
        {
            const float4 pa = *(const float4*)&palpha[(w * 64 + l) * 4];
            float alpha = (l < len) ? (pa.x + pa.y + pa.z + pa.w) : -INFINITY;
            float mx = alpha;
            #pragma unroll
            for (int d = 1; d < 64; d <<= 1) mx = fmaxf(mx, __shfl_xor(mx, d, 64));
            const float newm = fmaxf(m_run, mx);
            float e = (l < len) ? __expf(alpha - newm) : 0.f;
            float ss = e;
            #pragma unroll
            for (int d = 1; d < 64; d <<= 1) ss += __shfl_xor(ss, d, 64);
            const float sc = (m_run == -INFINITY) ? 0.f : __expf(m_run - newm);
            s_run = s_run * sc + ss;
            m_run = newm;
            wT[l * 4 + w] = e;
            if (l == 0) scale_lds[w] = sc;
        }
        __syncthreads();
        {
            const float4 scv = *(const float4*)scale_lds;
            acc4.x *= scv.x; acc4.y *= scv.y; acc4.z *= scv.z; acc4.w *= scv.w;
            const int j0 = jh * 32;
            const int j1 = min(len, j0 + 32);
            for (int j = j0; j < j1; j++) {
                const float hv = h_lds[c * 65 + j];
                const float4 wv = *(const float4*)&wT[j * 4];
                acc4.x = fmaf(wv.x, hv, acc4.x);
                acc4.y = fmaf(wv.y, hv, acc4.y);
                acc4.z = fmaf(wv.z, hv, acc4.z);
                acc4.w = fmaf(wv.w, hv, acc4.w);
            }
        }
    }
    if (l == 0) s_lds[w] = s_run;
    __syncthreads();            // all h_lds reads done -> merge may clobber
    if (jh == 1) *(float4*)&merge[c * 4] = acc4;
    __syncthreads();
    if (jh == 0) {
        const float4 o  = *(const float4*)&merge[c * 4];
        const float4 sv = *(const float4*)s_lds;
        g[(size_t)n * 512 + 0 * 128 + c] = (acc4.x + o.x) / (sv.x + 1e-16f);
        g[(size_t)n * 512 + 1 * 128 + c] = (acc4.y + o.y) / (sv.y + 1e-16f);
        g[(size_t)n * 512 + 2 * 128 + c] = (acc4.z + o.z) / (sv.z + 1e-16f);
        g[(size_t)n * 512 + 3 * 128 + c] = (acc4.w + o.w) / (sv.w + 1e-16f);
    }
}

// ---------------------------------------------------------------------------
// Radix-select sort-pool (exact, stable-tie; keys post-ReLU => uint-monotone)
// ---------------------------------------------------------------------------
__global__ __launch_bounds__(256) void radix_pool_kernel(
    const float* __restrict__ gkeys, const float* __restrict__ age,
    int* __restrict__ sel, float* __restrict__ z)
{
    __shared__ unsigned int keys[NN];
    __shared__ int hist[256];
    __shared__ int sbuf[256];
    __shared__ unsigned int sel_prefix;
    __shared__ int sel_need;
    __shared__ int gt_counter;
    __shared__ unsigned int cand_key[30];
    __shared__ int cand_idx[30];
    __shared__ int order[30];

    const int b = blockIdx.x;
    const int t = threadIdx.x;

    for (int i = t; i < NN; i += 256)
        keys[i] = __float_as_uint(gkeys[(size_t)b * NN + i]);
    if (t == 0) { sel_prefix = 0u; sel_need = 30; gt_counter = 0; }
    __syncthreads();

    for (int r = 3; r >= 0; r--) {
        hist[t] = 0;
        __syncthreads();
        const int shift = r * 8;
        const unsigned int pmask = (r == 3) ? 0u : (0xFFFFFFFFu << ((r + 1) * 8));
        const unsigned int pref = sel_prefix;
        const int need = sel_need;
        for (int i = t; i < NN; i += 256) {
            unsigned int k = keys[i];
            if ((k & pmask) == pref)
                atomicAdd(&hist[(k >> shift) & 255u], 1);
        }
        __syncthreads();
        sbuf[t] = hist[255 - t];
        __syncthreads();
        for (int d = 1; d < 256; d <<= 1) {
            int o = (t >= d) ? sbuf[t - d] : 0;
            __syncthreads();
            sbuf[t] += o;
            __syncthreads();
        }
        {
            const int v = t;
            const int ge = sbuf[255 - v];
            const int gt = ge - hist[v];
            if (gt < need && need <= ge) {
                sel_prefix = pref | ((unsigned int)v << shift);
                sel_need = need - gt;
            }
        }
        __syncthreads();
    }

    const unsigned int T = sel_prefix;
    const int need_eq = sel_need;
    const int n_gt = 30 - need_eq;

    for (int i = t; i < NN; i += 256) {
        unsigned int k = keys[i];
        if (k > T) {
            int p = atomicAdd(&gt_counter, 1);
            cand_key[p] = k; cand_idx[p] = i;
        }
    }
    {
        const int CHK = (NN + 255) / 256;
        const int i0 = t * CHK, i1 = min(NN, i0 + CHK);
        int local = 0;
        for (int i = i0; i < i1; i++) if (keys[i] == T) local++;
        sbuf[t] = local;
        __syncthreads();
        for (int d = 1; d < 256; d <<= 1) {
            int o = (t >= d) ? sbuf[t - d] : 0;
            __syncthreads();
            sbuf[t] += o;
            __syncthreads();
        }
        int rank = (t == 0) ? 0 : sbuf[t - 1];
        for (int i = i0; i < i1; i++) {
            if (keys[i] == T) {
                if (rank < need_eq) { cand_key[n_gt + rank] = T; cand_idx[n_gt + rank] = i; }
                rank++;
            }
        }
    }
    __syncthreads();
    if (t < 30) {
        const unsigned int mk = cand_key[t];
        const int mi = cand_idx[t];
        int rk = 0;
        for (int j = 0; j < 30; j++) {
            const unsigned int ok = cand_key[j];
            const int oi = cand_idx[j];
            if (ok > mk || (ok == mk && oi < mi)) rk++;
        }
        order[rk] = t;
    }
    __syncthreads();
    if (t < 30) sel[b * 30 + t] = cand_idx[order[t]];
    if (t == 0) z[(size_t)b * 3841 + 3840] = age[b];
}

// ---------------------------------------------------------------------------
// Build z rows: graph 0 copies from h3; graphs 1-7 recompute the 3-layer
// chain from x for the 30 winners (bit-identical ascending-k chains).
// ---------------------------------------------------------------------------
__global__ __launch_bounds__(128) void gather_kernel(
    const float* __restrict__ h3,     // lower NN rows valid
    const float* __restrict__ x,      // full NTOT x 128 input
    const float* __restrict__ Wskip, const float* __restrict__ bskip,
    const float* __restrict__ bnS, const float* __restrict__ bnB,
    const int* __restrict__ sel, float* __restrict__ z)
{
    __shared__ float buf0[128], buf1[128];
    const int blk = blockIdx.x;
    const int b = blk / 30;
    const int kk = blk % 30;
    const int c = threadIdx.x;
    const int i = sel[b * 30 + kk];
    const size_t g = (size_t)b * NN + i;
    float v;
    if (b == 0) {
        v = h3[g * CH + c];
    } else {
        float* rd = buf0;
        float* wr = buf1;
        buf0[c] = x[g * CH + c];
        __syncthreads();
        float s = 0.f;
        for (int l = 0; l < 3; l++) {
            s = 0.f;
            for (int k = 0; k < 128; k++) s = fmaf(rd[k], Wskip[k * 128 + c], s);
            s += bskip[c];
            s = fmaf(s, bnS[l * 128 + c], bnB[l * 128 + c]);
            s = fmaxf(s, 0.f);
            if (l < 2) {
                wr[c] = s;
                __syncthreads();
                float* tmp = rd; rd = wr; wr = tmp;
            }
        }
        v = s;
    }
    z[(size_t)b * 3841 + kk * CH + c] = v;
}

// ---------------------------------------------------------------------------
// MLP head
// ---------------------------------------------------------------------------
__global__ __launch_bounds__(256) void mlp1_kernel(
    const float* __restrict__ z, const float* __restrict__ W1,
    float* __restrict__ zh)
{
    __shared__ float zs[256];
    const int b  = blockIdx.x >> 4;
    const int ic = blockIdx.x & 15;
    const int t  = threadIdx.x;
    const int i0 = ic * 241;
    const int i1 = min(3841, i0 + 241);
    float a0 = 0.f, a1 = 0.f;
    for (int cb = i0; cb < i1; cb += 256) {
        int cl = min(256, i1 - cb);
        __syncthreads();
        if (t < cl) zs[t] = z[(size_t)b * 3841 + cb + t];
        __syncthreads();
        #pragma unroll 4
        for (int q = 0; q < cl; q++) {
            float zv = zs[q];
            const float* wp = W1 + (size_t)(cb + q) * 512;
            a0 = fmaf(zv, wp[t], a0);
            a1 = fmaf(zv, wp[t + 256], a1);
        }
    }
    atomicAdd(&zh[(size_t)b * 512 + t], a0);
    atomicAdd(&zh[(size_t)b * 512 + t + 256], a1);
}

__global__ __launch_bounds__(256) void mlp2_kernel(
    const float* __restrict__ zh, const float* __restrict__ b1,
    const float* __restrict__ W2, const float* __restrict__ b2,
    float* __restrict__ out)
{
    __shared__ float r0[256], r1[256];
    const int b = blockIdx.x;
    const int t = threadIdx.x;
    float a0 = 0.f, a1 = 0.f;
    for (int j = t; j < 512; j += 256) {
        float v = fmaxf(zh[(size_t)b * 512 + j] + b1[j], 0.f);
        a0 = fmaf(v, W2[j * 2 + 0], a0);
        a1 = fmaf(v, W2[j * 2 + 1], a1);
    }
    r0[t] = a0; r1[t] = a1; __syncthreads();
    for (int s = 128; s > 0; s >>= 1) {
        if (t < s) { r0[t] += r0[t + s]; r1[t] += r1[t + s]; }
        __syncthreads();
    }
    if (t == 0) {
        float l0 = r0[0] + b2[0], l1 = r1[0] + b2[1];
        float m = fmaxf(l0, l1);
        float lse = m + logf(__expf(l0 - m) + __expf(l1 - m));
        out[b * 2 + 0] = l0 - lse;
        out[b * 2 + 1] = l1 - lse;
    }
}

// ---------------------------------------------------------------------------
extern "C" void kernel_launch(void* const* d_in, const int* in_sizes, int n_in,
                              void* d_out, int out_size, void* d_ws, size_t ws_size,
                              hipStream_t stream) {
    const float* x     = (const float*)d_in[0];
    const int*   ei    = (const int*)d_in[1];
    const float* age   = (const float*)d_in[2];
    const float* Wq    = (const float*)d_in[3];
    const float* bq    = (const float*)d_in[4];
    const float* Wk    = (const float*)d_in[5];
    // d_in[6] = bk: provably softmax-invariant, unused.
    const float* Wv    = (const float*)d_in[7];
    const float* bv    = (const float*)d_in[8];
    const float* Wskip = (const float*)d_in[9];
    const float* bskip = (const float*)d_in[10];
    const float* bn_g  = (const float*)d_in[11];
    const float* bn_b  = (const float*)d_in[12];
    const float* bn_m  = (const float*)d_in[13];
    const float* bn_v  = (const float*)d_in[14];
    const float* W1    = (const float*)d_in[15];
    const float* b1    = (const float*)d_in[16];
    const float* W2    = (const float*)d_in[17];
    const float* b2    = (const float*)d_in[18];

    float* ws = (float*)d_ws;
    float* h3      = ws;                     // 10,240,000 (lower NN rows used)
    float* hlowA   = h3 + 10240000;          // 1,280,000
    float* hlowB   = hlowA + 1280000;        // 1,280,000
    float* u       = hlowB + 1280000;        // 5,120,000 (g aliases u)
    float* skipraw = u + 5120000;            // 1,280,000
    float* Bcat    = skipraw + 1280000;      // 81,920
    float* biascat = Bcat + 81920;           // 640
    float* Wcomb   = biascat + 640;          // 65,536
    float* bvbar   = Wcomb + 65536;          // 128
    float* bnS     = bvbar + 128;            // 384
    float* bnB     = bnS + 384;              // 384
    float* zbuf    = bnB + 384;              // 30,728
    float* zh      = zbuf + 30728;           // 4,096
    int* deg      = (int*)(zh + 4096);       // 10,000
    int* cursor   = deg + NN;                // 10,000
    int* rowstart = cursor + NN;             // 10,001
    int* csr_src  = rowstart + NN + 1;       // 320,000
    float* keysG  = (float*)(csr_src + EE);  // 80,000
    int* sel      = (int*)(keysG + NTOT);    // 240

    const int* srcI = ei;
    const int* dstI = ei + EE;

    hipMemsetAsync(deg, 0, sizeof(int) * (2 * NN), stream);   // deg + cursor
    hipMemsetAsync(zh, 0, sizeof(float) * 4096, stream);

    precompute_kernel<<<581, 256, 0, stream>>>(Wq, bq, Wk, Wv, bv, Wskip, bskip,
                                               bn_g, bn_b, bn_m, bn_v,
                                               Bcat, biascat, Wcomb, bvbar, bnS, bnB);
    count_kernel<<<1250, 256, 0, stream>>>(dstI, deg);
    scan_kernel<<<1, 1024, 0, stream>>>(deg, rowstart);
    scatter_kernel<<<1250, 256, 0, stream>>>(srcI, dstI, rowstart, cursor, csr_src);

    // upper 70000 rows: layers 1-2 + layer-3 keys (keys only)
    skip_keys_kernel<<<1094, 512, 0, stream>>>(x + (size_t)NN * CH, Wskip, bskip,
                                               bnS, bnB, keysG);

    const float* hcur = x;                   // lower-row slice (rows 0..NN-1)
    for (int l = 0; l < 3; l++) {
        float* dest = (l == 0) ? hlowA : (l == 1) ? hlowB : h3;  // h3 rows 0..NN-1
        // [u | raw skip] = h_low @ [Pm | Wskip] + [r | bskip]   (1570 blocks, BK=32)
        gemm_fp32<64, 64, 4, 4, 0, 32><<<dim3(157, 10), 256, 0, stream>>>(
            hcur, CH, Bcat, 640, biascat, nullptr, nullptr, nullptr,
            nullptr, nullptr, u, 512, skipraw, CH, NN, 128, nullptr);
        // g = softmax-weighted neighbor sums of h, aliased onto u
        attn_kernel<<<NN, 256, 0, stream>>>(hcur, u, u, rowstart, csr_src);
        // h_next = relu(bn(g @ Wvstack + skipraw + (deg>0)*bvbar))
        // r16: <16,64,1,4> -> grid (625,2) = 1250 blocks = 4.9/CU
        gemm_fp32<16, 64, 1, 4, 4, 32><<<dim3(625, 2), 256, 0, stream>>>(
            u, 512, Wcomb, CH, nullptr, bvbar, deg, skipraw,
            bnS + l * 128, bnB + l * 128, dest, CH, nullptr, CH, NN, 512,
            (l == 2) ? keysG : nullptr);
        hcur = dest;
    }
    radix_pool_kernel<<<8, 256, 0, stream>>>(keysG, age, sel, zbuf);
    gather_kernel<<<240, 128, 0, stream>>>(h3, x, Wskip, bskip,
                                           bnS, bnB, sel, zbuf);
    mlp1_kernel<<<128, 256, 0, stream>>>(zbuf, W1, zh);
    mlp2_kernel<<<8, 256, 0, stream>>>(zh, b1, W2, b2, (float*)d_out);
}

// Round 13
// 591.587 us; speedup vs baseline: 1.0354x; 1.0354x over previous
//
#include <hip/hip_runtime.h>
#include <cmath>

// MuSeGNN on MI355X — round 17: comb revert (r16 pre-commit) + skip/ugemm-L0
// fusion for cross-kernel pipe overlap.
//
// r16 post-mortem: comb <16,64,1,4> regressed +13 (TM=1: 4 FMAs per 18
// LDS-cyc = 9x oversubscription). comb <32,64,2,4> BK=32 restored; GEMM
// tile space now mapped on all sides. Remaining lever: the stream
// serializes skip_keys (76.5us, SCALAR-latency-bound, LDS idle) before
// ugemm-L0 (~33us, LDS-bound) though they're data-independent. Fused into
// one 512-thread launch: blocks 0..1093 = r13 skip verbatim; 1094+ =
// ugemm-L0 <32,128,2,4> BK=32 at 512 threads (1565 blocks). LDS union
// overlay 34.3KB -> 4 blocks/CU; ugemm role ~40 VGPR < 64 cap. Co-resident
// blocks fill each other's stall bubbles. Bit-exact: both bodies keep
// ascending-k chains + epilogues; block-level branch only.
// Pre-commit: fused ~= 109 (null) or ugemm-role regress -> revert to r15.
//
// Algebra (verified r1-r16, absmax 0.0): alpha_e = u[dst]·h[src] (+softmax-
// invariant const; bk drops), u = h·(Wq_h Wk_h^T/√C) + bq·Wk_h^T/√C.
// out[dst] = mean_h((Σ_e a_e h[src])·Wv_h + bv_h) + h@Wskip + bskip; deg=0
// rows lose the attention term AND bv (empty segment sum).

#define NN    10000
#define NTOT  80000
#define EE    320000
#define CH    128

__device__ __forceinline__ float rl_f(float v, int lane) {
    return __uint_as_float(__builtin_amdgcn_readlane(__float_as_uint(v), lane));
}

// ---------------------------------------------------------------------------
// Precompute: Bcat (128x640 = [Pm | Wskip]), biascat (640 = [r | bskip]),
// Wcomb (512x128 = Wv/4 stacked (h,c)-major), bvbar, BN scale/bias.
// ---------------------------------------------------------------------------
__global__ __launch_bounds__(256) void precompute_kernel(
    const float* __restrict__ Wq, const float* __restrict__ bq,
    const float* __restrict__ Wk, const float* __restrict__ Wv,
    const float* __restrict__ bv, const float* __restrict__ Wskip,
    const float* __restrict__ bskip,
    const float* __restrict__ bn_gamma, const float* __restrict__ bn_beta,
    const float* __restrict__ bn_mean, const float* __restrict__ bn_var,
    float* __restrict__ Bcat, float* __restrict__ biascat,
    float* __restrict__ Wcomb, float* __restrict__ bvbar,
    float* __restrict__ bnS, float* __restrict__ bnB)
{
    const float inv_sqrtC = 0.08838834764831845f;  // 1/sqrt(128)
    int idx = blockIdx.x * 256 + threadIdx.x;
    if (idx < 65536) {            // Pm part: Bcat[c, o] o<512
        int c = idx >> 9;
        int o = idx & 511;
        int hbase = o & ~127;
        int j = o & 127;
        const float* wq = Wq + c * 512 + hbase;
        const float* wk = Wk + j * 512 + hbase;
        float s = 0.f;
        for (int cc = 0; cc < 128; cc++) s = fmaf(wq[cc], wk[cc], s);
        Bcat[c * 640 + o] = s * inv_sqrtC;
        return;
    }
    idx -= 65536;
    if (idx < 16384) {            // Wskip part: Bcat[c, 512+n]
        int c = idx >> 7, n = idx & 127;
        Bcat[c * 640 + 512 + n] = Wskip[c * 128 + n];
        return;
    }
    idx -= 16384;
    if (idx < 512) {              // biascat[0..511] = r
        int o = idx, hbase = o & ~127, j = o & 127;
        const float* wk = Wk + j * 512 + hbase;
        const float* bqp = bq + hbase;
        float s = 0.f;
        for (int cc = 0; cc < 128; cc++) s = fmaf(bqp[cc], wk[cc], s);
        biascat[o] = s * inv_sqrtC;
        return;
    }
    idx -= 512;
    if (idx < 128) {              // biascat[512..639] = bskip
        biascat[512 + idx] = bskip[idx];
        return;
    }
    idx -= 128;
    if (idx < 65536) {            // Wcomb[k, n], k=(h,c): Wv[c, h*128+n] / 4
        int k = idx >> 7;
        int n = idx & 127;
        int h = k >> 7, c = k & 127;
        Wcomb[k * 128 + n] = Wv[c * 512 + h * 128 + n] * 0.25f;
        return;
    }
    idx -= 65536;
    if (idx < 128) {              // bvbar = mean over heads of bv
        float s = 0.f;
        for (int h = 0; h < 4; h++) s += bv[h * 128 + idx];
        bvbar[idx] = 0.25f * s;
        return;
    }
    idx -= 128;
    if (idx < 384) {              // BN fold (eval): y = x*scale + bias
        float sc = bn_gamma[idx] / sqrtf(bn_var[idx] + 1e-5f);
        bnS[idx] = sc;
        bnB[idx] = bn_beta[idx] - bn_mean[idx] * sc;
        return;
    }
}

// ---------------------------------------------------------------------------
// CSR build by dst
// ---------------------------------------------------------------------------
__global__ void count_kernel(const int* __restrict__ dst, int* __restrict__ deg) {
    int e = blockIdx.x * 256 + threadIdx.x;
    if (e < EE) atomicAdd(&deg[dst[e]], 1);
}

__global__ __launch_bounds__(1024) void scan_kernel(const int* __restrict__ deg,
                                                    int* __restrict__ rowstart) {
    __shared__ int part[1024];
    const int t = threadIdx.x;
    int loc[10];
    int s = 0;
    for (int i = 0; i < 10; i++) {
        int idx = t * 10 + i;
        int v = (idx < NN) ? deg[idx] : 0;
        loc[i] = s; s += v;
    }
    part[t] = s; __syncthreads();
    for (int d = 1; d < 1024; d <<= 1) {
        int v = (t >= d) ? part[t - d] : 0;
        __syncthreads();
        part[t] += v;
        __syncthreads();
    }
    int base = (t == 0) ? 0 : part[t - 1];
    for (int i = 0; i < 10; i++) {
        int idx = t * 10 + i;
        if (idx <= NN) rowstart[idx] = base + loc[i];
    }
}

__global__ void scatter_kernel(const int* __restrict__ src, const int* __restrict__ dst,
                               const int* __restrict__ rowstart, int* __restrict__ cursor,
                               int* __restrict__ csr_src) {
    int e = blockIdx.x * 256 + threadIdx.x;
    if (e < EE) {
        int d = dst[e];
        int p = atomicAdd(&cursor[d], 1);
        csr_src[rowstart[d] + p] = src[e];
    }
}

// ---------------------------------------------------------------------------
// Fused L0 kernel, 512 threads:
//  blocks 0..1093     : skip_keys role (r13 code verbatim; scalar-bound)
//  blocks 1094..2658  : ugemm-L0 role <BM=32,BN=128,TM=2,TN=4,BK=32>
//                       (LDS-bound) — u = x_low @ Pm + r, cols>=512 -> skipraw
// LDS union overlay (34.3KB). Both roles keep ascending-k chains -> bit-exact.
// ---------------------------------------------------------------------------
#define FUSED_SKIP_BLOCKS 1094
__global__ __launch_bounds__(512, 4) void fused_l0_kernel(
    const float* __restrict__ x,      // NTOT x 128
    const float* __restrict__ Wskip,
    const float* __restrict__ bskip,
    const float* __restrict__ bnS, const float* __restrict__ bnB,
    float* __restrict__ gkeys,
    const float* __restrict__ Bcat, const float* __restrict__ biascat,
    float* __restrict__ u, float* __restrict__ skipraw)
{
    __shared__ __align__(16) char smem[34816];
    const int bx = blockIdx.x;
    const int t = threadIdx.x;

    if (bx < FUSED_SKIP_BLOCKS) {
        // ---------------- skip role (r13, verbatim) ----------------
        float (*rowb)[132] = (float(*)[132])smem;
        float* sWc = (float*)(smem + 64 * 132 * 4);
        const float* xup = x + (size_t)NN * CH;
        const int l = t & 63;
        const int wv = __builtin_amdgcn_readfirstlane(t >> 6);
        const int colbase = wv * 16;
        const int r0 = bx * 64;
        const int Mrem = min(64, (NTOT - NN) - r0);

        for (int f = t; f < 64 * 32; f += 512) {
            int row = f >> 5, c4 = (f & 31) * 4;
            float4 v = make_float4(0.f, 0.f, 0.f, 0.f);
            if (row < Mrem) v = *(const float4*)(xup + (size_t)(r0 + row) * CH + c4);
            *(float4*)&rowb[row][c4] = v;
        }
        if (t < 128) sWc[t] = Wskip[t * 128 + 127];
        __syncthreads();

        for (int layer = 0; layer < 2; layer++) {
            float acc[16];
            #pragma unroll
            for (int c = 0; c < 16; c++) acc[c] = 0.f;
            const float* Wb = Wskip + colbase;
            for (int kq = 0; kq < 32; kq++) {
                const float4 a4 = *(const float4*)&rowb[l][kq * 4];
                #pragma unroll
                for (int q = 0; q < 4; q++) {
                    const float av = (q == 0) ? a4.x : (q == 1) ? a4.y
                                   : (q == 2) ? a4.z : a4.w;
                    const float* wr = Wb + (kq * 4 + q) * 128;
                    #pragma unroll
                    for (int c = 0; c < 16; c++)
                        acc[c] = fmaf(av, wr[c], acc[c]);
                }
            }
            __syncthreads();
            const float* bS = bnS + layer * 128;
            const float* bB = bnB + layer * 128;
            #pragma unroll
            for (int c4 = 0; c4 < 4; c4++) {
                float4 v;
                float* vp = &v.x;
                #pragma unroll
                for (int q = 0; q < 4; q++) {
                    const int n = colbase + c4 * 4 + q;
                    float xv = acc[c4 * 4 + q] + bskip[n];
                    xv = fmaf(xv, bS[n], bB[n]);
                    vp[q] = fmaxf(xv, 0.f);
                }
                *(float4*)&rowb[l][colbase + c4 * 4] = v;
            }
            __syncthreads();
        }
        if (t < Mrem) {
            float s = 0.f;
            for (int k = 0; k < 128; k++) s = fmaf(rowb[t][k], sWc[k], s);
            s += bskip[127];
            s = fmaf(s, bnS[2 * 128 + 127], bnB[2 * 128 + 127]);
            gkeys[NN + r0 + t] = fmaxf(s, 0.f);
        }
    } else {
        // ---------------- ugemm-L0 role <32,128,2,4> BK=32 ----------------
        float (*As)[36]  = (float(*)[36])smem;                 // 32 x 36
        float (*Bs)[132] = (float(*)[132])(smem + 32 * 36 * 4);// 32 x 132
        const int ub = bx - FUSED_SKIP_BLOCKS;
        const int m0 = (ub / 5) * 32;
        const int n0 = (ub % 5) * 128;
        const int tx = t & 31;          // 32 col-groups (BN/TN = 32)
        const int ty = t >> 5;          // 16 row-groups x TM=2

        float acc[2][4];
        #pragma unroll
        for (int i = 0; i < 2; i++)
            #pragma unroll
            for (int j = 0; j < 4; j++) acc[i][j] = 0.f;

        for (int k0 = 0; k0 < 128; k0 += 32) {
            for (int f = t; f < 32 * 8; f += 512) {     // 256 float4 A-loads
                int row = f >> 3, fc = f & 7;
                int gm = m0 + row;
                float4 v = make_float4(0.f, 0.f, 0.f, 0.f);
                if (gm < NN) v = *(const float4*)(x + (size_t)gm * CH + k0 + fc * 4);
                As[fc * 4 + 0][row] = v.x;
                As[fc * 4 + 1][row] = v.y;
                As[fc * 4 + 2][row] = v.z;
                As[fc * 4 + 3][row] = v.w;
            }
            for (int f = t; f < 32 * 32; f += 512) {    // 1024 float4 B-loads
                int kk = f >> 5;
                int nn = (f & 31) * 4;
                *(float4*)(&Bs[kk][nn]) =
                    *(const float4*)(Bcat + (size_t)(k0 + kk) * 640 + n0 + nn);
            }
            __syncthreads();
            #pragma unroll
            for (int kk = 0; kk < 32; kk++) {
                const float2 a2 = *(const float2*)&As[kk][ty * 2];
                const float4 b4 = *(const float4*)&Bs[kk][tx * 4];
                acc[0][0] = fmaf(a2.x, b4.x, acc[0][0]);
                acc[0][1] = fmaf(a2.x, b4.y, acc[0][1]);
                acc[0][2] = fmaf(a2.x, b4.z, acc[0][2]);
                acc[0][3] = fmaf(a2.x, b4.w, acc[0][3]);
                acc[1][0] = fmaf(a2.y, b4.x, acc[1][0]);
                acc[1][1] = fmaf(a2.y, b4.y, acc[1][1]);
                acc[1][2] = fmaf(a2.y, b4.z, acc[1][2]);
                acc[1][3] = fmaf(a2.y, b4.w, acc[1][3]);
            }
            __syncthreads();
        }
        #pragma unroll
        for (int i = 0; i < 2; i++) {
            const int gm = m0 + ty * 2 + i;
            if (gm >= NN) continue;
            const int nb = n0 + tx * 4;
            float4 v;
            float* vp = &v.x;
            #pragma unroll
            for (int q = 0; q < 4; q++)
                vp[q] = acc[i][q] + biascat[nb + q];
            if (nb < 512)
                *(float4*)(u + (size_t)gm * 512 + nb) = v;
            else
                *(float4*)(skipraw + (size_t)gm * CH + nb - 512) = v;
        }
    }
}

// ---------------------------------------------------------------------------
// fp32 tiled GEMM, 256 threads, BK template — BK=32 in use. TM in {2,4}.
// MODE 0 (ug): C = A*B + bias, dual dest: cols <512 -> C0 (u), >=512 -> C1.
// MODE 4 (comb'): C0 = relu(bn(A*B + Cold + (deg>0)*bias2)); optionally
//              mirrors col 127 into keysOut (for the final layer).
// ---------------------------------------------------------------------------
template<int BM, int BN, int TM, int TN, int MODE, int BK>
__global__ __launch_bounds__(256) void gemm_fp32(
    const float* __restrict__ A, int lda,
    const float* __restrict__ B, int ldb,
    const float* __restrict__ bias, const float* __restrict__ bias2,
    const int* __restrict__ deg,
    const float* __restrict__ Cold,
    const float* __restrict__ bnS, const float* __restrict__ bnB,
    float* __restrict__ C0, int ldc0,
    float* __restrict__ C1, int ldc1,
    int M, int K,
    float* __restrict__ keysOut)
{
    constexpr int KF = BK / 4;           // float4s per row per k-tile
    __shared__ float As[BK][BM + 4];
    __shared__ float Bs[BK][BN + 4];
    const int t  = threadIdx.x;
    const int tx = t % (BN / TN);
    const int ty = t / (BN / TN);
    const int m0 = blockIdx.x * BM;
    const int n0 = blockIdx.y * BN;
    float acc[TM][TN];
    #pragma unroll
    for (int i = 0; i < TM; i++)
        #pragma unroll
        for (int j = 0; j < TN; j++) acc[i][j] = 0.f;

    for (int k0 = 0; k0 < K; k0 += BK) {
        #pragma unroll
        for (int f = t; f < BM * KF; f += 256) {
            int row = f / KF, fc = f % KF;
            int gm = m0 + row;
            float4 v = make_float4(0.f, 0.f, 0.f, 0.f);
            if (gm < M) v = *(const float4*)(A + (size_t)gm * lda + k0 + fc * 4);
            As[fc * 4 + 0][row] = v.x;
            As[fc * 4 + 1][row] = v.y;
            As[fc * 4 + 2][row] = v.z;
            As[fc * 4 + 3][row] = v.w;
        }
        #pragma unroll
        for (int f = t; f < BK * (BN / 4); f += 256) {
            int kk = f / (BN / 4);
            int nn = (f % (BN / 4)) * 4;
            *(float4*)(&Bs[kk][nn]) = *(const float4*)(B + (size_t)(k0 + kk) * ldb + n0 + nn);
        }
        __syncthreads();
        #pragma unroll
        for (int kk = 0; kk < BK; kk++) {
            float af[TM], bf[TN];
            if constexpr (TM == 2) {
                float2 v = *(const float2*)&As[kk][ty * 2];
                af[0] = v.x; af[1] = v.y;
            } else {  // TM == 4
                float4 v = *(const float4*)&As[kk][ty * 4];
                af[0] = v.x; af[1] = v.y; af[2] = v.z; af[3] = v.w;
            }
            if constexpr (TN == 4) {
                float4 v = *(const float4*)&Bs[kk][tx * 4];
                bf[0] = v.x; bf[1] = v.y; bf[2] = v.z; bf[3] = v.w;
            } else {  // TN == 8: split cols
                float4 v = *(const float4*)&Bs[kk][tx * 4];
                float4 w = *(const float4*)&Bs[kk][BN / 2 + tx * 4];
                bf[0] = v.x; bf[1] = v.y; bf[2] = v.z; bf[3] = v.w;
                bf[4] = w.x; bf[5] = w.y; bf[6] = w.z; bf[7] = w.w;
            }
            #pragma unroll
            for (int i = 0; i < TM; i++)
                #pragma unroll
                for (int j = 0; j < TN; j++)
                    acc[i][j] = fmaf(af[i], bf[j], acc[i][j]);
        }
        __syncthreads();
    }
    // epilogue
    #pragma unroll
    for (int i = 0; i < TM; i++) {
        const int gm = m0 + ty * TM + i;
        if (gm >= M) continue;
        const bool addB2 = (MODE == 4) ? (deg[gm] > 0) : false;
        #pragma unroll
        for (int h = 0; h < TN / 4; h++) {
            const int nb = n0 + ((TN == 8) ? h * (BN / 2) + tx * 4 : tx * TN + h * 4);
            float4 v;
            float* vp = &v.x;
            if (MODE == 4) {
                const float4 old = *(const float4*)(Cold + (size_t)gm * ldc1 + nb);
                const float* op = &old.x;
                #pragma unroll
                for (int q = 0; q < 4; q++) {
                    const int n = nb + q;
                    float x = acc[i][h * 4 + q] + op[q];
                    if (addB2) x += bias2[n];
                    x = fmaf(x, bnS[n], bnB[n]);
                    vp[q] = fmaxf(x, 0.f);
                }
                *(float4*)(C0 + (size_t)gm * ldc0 + nb) = v;
                if (keysOut != nullptr && nb == 124) keysOut[gm] = v.w;  // col 127
            } else {
                #pragma unroll
                for (int q = 0; q < 4; q++)
                    vp[q] = acc[i][h * 4 + q] + bias[nb + q];
                if (nb < 512)
                    *(float4*)(C0 + (size_t)gm * ldc0 + nb) = v;
                else
                    *(float4*)(C1 + (size_t)gm * ldc1 + nb - 512) = v;
            }
        }
    }
}

// ---------------------------------------------------------------------------
// Attention: one block per dst node, chunked online softmax over CSR edges.
// (r13 version: src_lds staging; merge aliased onto h_lds -> 4 blocks/CU.)
// ---------------------------------------------------------------------------
__global__ __launch_bounds__(256) void attn_kernel(
    const float* __restrict__ h,
    const float* __restrict__ u,
    float* __restrict__ g,
    const int* __restrict__ rowstart,
    const int* __restrict__ csr_src)
{
    __shared__ __align__(16) float h_lds[128 * 65];
    __shared__ __align__(16) float palpha[4 * 64 * 4];   // [ht][j][w]
    __shared__ __align__(16) float wT[64 * 4];           // [j][ht]
    __shared__ __align__(16) float scale_lds[4];
    __shared__ __align__(16) float s_lds[4];
    __shared__ int src_lds[64];
    float* merge = h_lds;       // aliased: only live after the chunk loop

    const int n  = blockIdx.x;
    const int t  = threadIdx.x;
    const int w  = t >> 6;      // wave id
    const int l  = t & 63;      // lane
    const int c  = t & 127;     // acc channel
    const int jh = t >> 7;      // acc j-half
    const int rs   = rowstart[n];
    const int degn = rowstart[n + 1] - rs;

    if (degn == 0) {
        g[(size_t)n * 512 + t] = 0.f;
        g[(size_t)n * 512 + 256 + t] = 0.f;
        return;
    }
    float u_reg0 = u[(size_t)n * 512 + ((l >> 5)) * 128 + 32 * w + (l & 31)];
    float u_reg1 = u[(size_t)n * 512 + ((l >> 5) + 2) * 128 + 32 * w + (l & 31)];

    float m_run = -INFINITY, s_run = 0.f;
    float4 acc4 = make_float4(0.f, 0.f, 0.f, 0.f);

    for (int base = 0; base < degn; base += 64) {
        const int len = min(64, degn - base);
        __syncthreads();
        if (t < len) src_lds[t] = csr_src[rs + base + t];
        __syncthreads();
        for (int f = t; f < len * 32; f += 256) {
            const int j = f >> 5, c4 = (f & 31) * 4;
            const float4 v = *(const float4*)(h + (size_t)src_lds[j] * CH + c4);
            h_lds[(c4 + 0) * 65 + j] = v.x;
            h_lds[(c4 + 1) * 65 + j] = v.y;
            h_lds[(c4 + 2) * 65 + j] = v.z;
            h_lds[(c4 + 3) * 65 + j] = v.w;
        }
        __syncthreads();
        {
            float p0 = 0.f, p1 = 0.f, p2 = 0.f, p3 = 0.f;
            #pragma unroll
            for (int dc = 0; dc < 32; dc++) {
                const float hv = h_lds[(32 * w + dc) * 65 + l];
                p0 = fmaf(rl_f(u_reg0, dc),      hv, p0);
                p1 = fmaf(rl_f(u_reg0, 32 + dc), hv, p1);
                p2 = fmaf(rl_f(u_reg1, dc),      hv, p2);
                p3 = fmaf(rl_f(u_reg1, 32 + dc), hv, p3);
            }
            palpha[(0 * 64 + l) * 4 + w] = p0;
            palpha[(1 * 64 + l) * 4 + w] = p1;
            palpha[(2 * 64 + l) * 4 + w] = p2;
            palpha[(3 * 64 + l) * 4 + w] = p3;
        }
        __syncthreads();
        {
            const float4 pa = *(const float4*)&palpha[(w * 64 + l) * 4];
            float alpha = (l < len) ? (pa.x + pa.y + pa.z + pa.w) : -INFINITY;
            float mx = alpha;
            #pragma unroll
            for (int d = 1; d < 64; d <<= 1) mx = fmaxf(mx, __shfl_xor(mx, d, 64));
            const float newm = fmaxf(m_run, mx);
            float e = (l < len) ? __expf(alpha - newm) : 0.f;
            float ss = e;
            #pragma unroll
            for (int d = 1; d < 64; d <<= 1) ss += __shfl_xor(ss, d, 64);
            const float sc = (m_run == -INFINITY) ? 0.f : __expf(m_run - newm);
            s_run = s_run * sc + ss;
            m_run = newm;
            wT[l * 4 + w] = e;
            if (l == 0) scale_lds[w] = sc;
        }
        __syncthreads();
        {
            const float4 scv = *(const float4*)scale_lds;
            acc4.x *= scv.x; acc4.y *= scv.y; acc4.z *= scv.z; acc4.w *= scv.w;
            const int j0 = jh * 32;
            const int j1 = min(len, j0 + 32);
            for (int j = j0; j < j1; j++) {
                const float hv = h_lds[c * 65 + j];
                const float4 wv = *(const float4*)&wT[j * 4];
                acc4.x = fmaf(wv.x, hv, acc4.x);
                acc4.y = fmaf(wv.y, hv, acc4.y);
                acc4.z = fmaf(wv.z, hv, acc4.z);
                acc4.w = fmaf(wv.w, hv, acc4.w);
            }
        }
    }
    if (l == 0) s_lds[w] = s_run;
    __syncthreads();            // all h_lds reads done -> merge may clobber
    if (jh == 1) *(float4*)&merge[c * 4] = acc4;
    __syncthreads();
    if (jh == 0) {
        const float4 o  = *(const float4*)&merge[c * 4];
        const float4 sv = *(const float4*)s_lds;
        g[(size_t)n * 512 + 0 * 128 + c] = (acc4.x + o.x) / (sv.x + 1e-16f);
        g[(size_t)n * 512 + 1 * 128 + c] = (acc4.y + o.y) / (sv.y + 1e-16f);
        g[(size_t)n * 512 + 2 * 128 + c] = (acc4.z + o.z) / (sv.z + 1e-16f);
        g[(size_t)n * 512 + 3 * 128 + c] = (acc4.w + o.w) / (sv.w + 1e-16f);
    }
}

// ---------------------------------------------------------------------------
// Radix-select sort-pool (exact, stable-tie; keys post-ReLU => uint-monotone)
// ---------------------------------------------------------------------------
__global__ __launch_bounds__(256) void radix_pool_kernel(
    const float* __restrict__ gkeys, const float* __restrict__ age,
    int* __restrict__ sel, float* __restrict__ z)
{
    __shared__ unsigned int keys[NN];
    __shared__ int hist[256];
    __shared__ int sbuf[256];
    __shared__ unsigned int sel_prefix;
    __shared__ int sel_need;
    __shared__ int gt_counter;
    __shared__ unsigned int cand_key[30];
    __shared__ int cand_idx[30];
    __shared__ int order[30];

    const int b = blockIdx.x;
    const int t = threadIdx.x;

    for (int i = t; i < NN; i += 256)
        keys[i] = __float_as_uint(gkeys[(size_t)b * NN + i]);
    if (t == 0) { sel_prefix = 0u; sel_need = 30; gt_counter = 0; }
    __syncthreads();

    for (int r = 3; r >= 0; r--) {
        hist[t] = 0;
        __syncthreads();
        const int shift = r * 8;
        const unsigned int pmask = (r == 3) ? 0u : (0xFFFFFFFFu << ((r + 1) * 8));
        const unsigned int pref = sel_prefix;
        const int need = sel_need;
        for (int i = t; i < NN; i += 256) {
            unsigned int k = keys[i];
            if ((k & pmask) == pref)
                atomicAdd(&hist[(k >> shift) & 255u], 1);
        }
        __syncthreads();
        sbuf[t] = hist[255 - t];
        __syncthreads();
        for (int d = 1; d < 256; d <<= 1) {
            int o = (t >= d) ? sbuf[t - d] : 0;
            __syncthreads();
            sbuf[t] += o;
            __syncthreads();
        }
        {
            const int v = t;
            const int ge = sbuf[255 - v];
            const int gt = ge - hist[v];
            if (gt < need && need <= ge) {
                sel_prefix = pref | ((unsigned int)v << shift);
                sel_need = need - gt;
            }
        }
        __syncthreads();
    }

    const unsigned int T = sel_prefix;
    const int need_eq = sel_need;
    const int n_gt = 30 - need_eq;

    for (int i = t; i < NN; i += 256) {
        unsigned int k = keys[i];
        if (k > T) {
            int p = atomicAdd(&gt_counter, 1);
            cand_key[p] = k; cand_idx[p] = i;
        }
    }
    {
        const int CHK = (NN + 255) / 256;
        const int i0 = t * CHK, i1 = min(NN, i0 + CHK);
        int local = 0;
        for (int i = i0; i < i1; i++) if (keys[i] == T) local++;
        sbuf[t] = local;
        __syncthreads();
        for (int d = 1; d < 256; d <<= 1) {
            int o = (t >= d) ? sbuf[t - d] : 0;
            __syncthreads();
            sbuf[t] += o;
            __syncthreads();
        }
        int rank = (t == 0) ? 0 : sbuf[t - 1];
        for (int i = i0; i < i1; i++) {
            if (keys[i] == T) {
                if (rank < need_eq) { cand_key[n_gt + rank] = T; cand_idx[n_gt + rank] = i; }
                rank++;
            }
        }
    }
    __syncthreads();
    if (t < 30) {
        const unsigned int mk = cand_key[t];
        const int mi = cand_idx[t];
        int rk = 0;
        for (int j = 0; j < 30; j++) {
            const unsigned int ok = cand_key[j];
            const int oi = cand_idx[j];
            if (ok > mk || (ok == mk && oi < mi)) rk++;
        }
        order[rk] = t;
    }
    __syncthreads();
    if (t < 30) sel[b * 30 + t] = cand_idx[order[t]];
    if (t == 0) z[(size_t)b * 3841 + 3840] = age[b];
}

// ---------------------------------------------------------------------------
// Build z rows: graph 0 copies from h3; graphs 1-7 recompute the 3-layer
// chain from x for the 30 winners (bit-identical ascending-k chains).
// ---------------------------------------------------------------------------
__global__ __launch_bounds__(128) void gather_kernel(
    const float* __restrict__ h3,     // lower NN rows valid
    const float* __restrict__ x,      // full NTOT x 128 input
    const float* __restrict__ Wskip, const float* __restrict__ bskip,
    const float* __restrict__ bnS, const float* __restrict__ bnB,
    const int* __restrict__ sel, float* __restrict__ z)
{
    __shared__ float buf0[128], buf1[128];
    const int blk = blockIdx.x;
    const int b = blk / 30;
    const int kk = blk % 30;
    const int c = threadIdx.x;
    const int i = sel[b * 30 + kk];
    const size_t g = (size_t)b * NN + i;
    float v;
    if (b == 0) {
        v = h3[g * CH + c];
    } else {
        float* rd = buf0;
        float* wr = buf1;
        buf0[c] = x[g * CH + c];
        __syncthreads();
        float s = 0.f;
        for (int l = 0; l < 3; l++) {
            s = 0.f;
            for (int k = 0; k < 128; k++) s = fmaf(rd[k], Wskip[k * 128 + c], s);
            s += bskip[c];
            s = fmaf(s, bnS[l * 128 + c], bnB[l * 128 + c]);
            s = fmaxf(s, 0.f);
            if (l < 2) {
                wr[c] = s;
                __syncthreads();
                float* tmp = rd; rd = wr; wr = tmp;
            }
        }
        v = s;
    }
    z[(size_t)b * 3841 + kk * CH + c] = v;
}

// ---------------------------------------------------------------------------
// MLP head
// ---------------------------------------------------------------------------
__global__ __launch_bounds__(256) void mlp1_kernel(
    const float* __restrict__ z, const float* __restrict__ W1,
    float* __restrict__ zh)
{
    __shared__ float zs[256];
    const int b  = blockIdx.x >> 4;
    const int ic = blockIdx.x & 15;
    const int t  = threadIdx.x;
    const int i0 = ic * 241;
    const int i1 = min(3841, i0 + 241);
    float a0 = 0.f, a1 = 0.f;
    for (int cb = i0; cb < i1; cb += 256) {
        int cl = min(256, i1 - cb);
        __syncthreads();
        if (t < cl) zs[t] = z[(size_t)b * 3841 + cb + t];
        __syncthreads();
        #pragma unroll 4
        for (int q = 0; q < cl; q++) {
            float zv = zs[q];
            const float* wp = W1 + (size_t)(cb + q) * 512;
            a0 = fmaf(zv, wp[t], a0);
            a1 = fmaf(zv, wp[t + 256], a1);
        }
    }
    atomicAdd(&zh[(size_t)b * 512 + t], a0);
    atomicAdd(&zh[(size_t)b * 512 + t + 256], a1);
}

__global__ __launch_bounds__(256) void mlp2_kernel(
    const float* __restrict__ zh, const float* __restrict__ b1,
    const float* __restrict__ W2, const float* __restrict__ b2,
    float* __restrict__ out)
{
    __shared__ float r0[256], r1[256];
    const int b = blockIdx.x;
    const int t = threadIdx.x;
    float a0 = 0.f, a1 = 0.f;
    for (int j = t; j < 512; j += 256) {
        float v = fmaxf(zh[(size_t)b * 512 + j] + b1[j], 0.f);
        a0 = fmaf(v, W2[j * 2 + 0], a0);
        a1 = fmaf(v, W2[j * 2 + 1], a1);
    }
    r0[t] = a0; r1[t] = a1; __syncthreads();
    for (int s = 128; s > 0; s >>= 1) {
        if (t < s) { r0[t] += r0[t + s]; r1[t] += r1[t + s]; }
        __syncthreads();
    }
    if (t == 0) {
        float l0 = r0[0] + b2[0], l1 = r1[0] + b2[1];
        float m = fmaxf(l0, l1);
        float lse = m + logf(__expf(l0 - m) + __expf(l1 - m));
        out[b * 2 + 0] = l0 - lse;
        out[b * 2 + 1] = l1 - lse;
    }
}

// ---------------------------------------------------------------------------
extern "C" void kernel_launch(void* const* d_in, const int* in_sizes, int n_in,
                              void* d_out, int out_size, void* d_ws, size_t ws_size,
                              hipStream_t stream) {
    const float* x     = (const float*)d_in[0];
    const int*   ei    = (const int*)d_in[1];
    const float* age   = (const float*)d_in[2];
    const float* Wq    = (const float*)d_in[3];
    const float* bq    = (const float*)d_in[4];
    const float* Wk    = (const float*)d_in[5];
    // d_in[6] = bk: provably softmax-invariant, unused.
    const float* Wv    = (const float*)d_in[7];
    const float* bv    = (const float*)d_in[8];
    const float* Wskip = (const float*)d_in[9];
    const float* bskip = (const float*)d_in[10];
    const float* bn_g  = (const float*)d_in[11];
    const float* bn_b  = (const float*)d_in[12];
    const float* bn_m  = (const float*)d_in[13];
    const float* bn_v  = (const float*)d_in[14];
    const float* W1    = (const float*)d_in[15];
    const float* b1    = (const float*)d_in[16];
    const float* W2    = (const float*)d_in[17];
    const float* b2    = (const float*)d_in[18];

    float* ws = (float*)d_ws;
    float* h3      = ws;                     // 10,240,000 (lower NN rows used)
    float* hlowA   = h3 + 10240000;          // 1,280,000
    float* hlowB   = hlowA + 1280000;        // 1,280,000
    float* u       = hlowB + 1280000;        // 5,120,000 (g aliases u)
    float* skipraw = u + 5120000;            // 1,280,000
    float* Bcat    = skipraw + 1280000;      // 81,920
    float* biascat = Bcat + 81920;           // 640
    float* Wcomb   = biascat + 640;          // 65,536
    float* bvbar   = Wcomb + 65536;          // 128
    float* bnS     = bvbar + 128;            // 384
    float* bnB     = bnS + 384;              // 384
    float* zbuf    = bnB + 384;              // 30,728
    float* zh      = zbuf + 30728;           // 4,096
    int* deg      = (int*)(zh + 4096);       // 10,000
    int* cursor   = deg + NN;                // 10,000
    int* rowstart = cursor + NN;             // 10,001
    int* csr_src  = rowstart + NN + 1;       // 320,000
    float* keysG  = (float*)(csr_src + EE);  // 80,000
    int* sel      = (int*)(keysG + NTOT);    // 240

    const int* srcI = ei;
    const int* dstI = ei + EE;

    hipMemsetAsync(deg, 0, sizeof(int) * (2 * NN), stream);   // deg + cursor
    hipMemsetAsync(zh, 0, sizeof(float) * 4096, stream);

    precompute_kernel<<<581, 256, 0, stream>>>(Wq, bq, Wk, Wv, bv, Wskip, bskip,
                                               bn_g, bn_b, bn_m, bn_v,
                                               Bcat, biascat, Wcomb, bvbar, bnS, bnB);
    count_kernel<<<1250, 256, 0, stream>>>(dstI, deg);
    scan_kernel<<<1, 1024, 0, stream>>>(deg, rowstart);
    scatter_kernel<<<1250, 256, 0, stream>>>(srcI, dstI, rowstart, cursor, csr_src);

    // Fused: skip_keys (blocks 0..1093) + ugemm layer-0 (blocks 1094..2658)
    fused_l0_kernel<<<FUSED_SKIP_BLOCKS + 1565, 512, 0, stream>>>(
        x, Wskip, bskip, bnS, bnB, keysG, Bcat, biascat, u, skipraw);

    const float* hcur = x;                   // lower-row slice (rows 0..NN-1)
    for (int l = 0; l < 3; l++) {
        float* dest = (l == 0) ? hlowA : (l == 1) ? hlowB : h3;  // h3 rows 0..NN-1
        if (l > 0) {
            // [u | raw skip] = h_low @ [Pm | Wskip] + [r | bskip] (1570 blocks)
            gemm_fp32<64, 64, 4, 4, 0, 32><<<dim3(157, 10), 256, 0, stream>>>(
                hcur, CH, Bcat, 640, biascat, nullptr, nullptr, nullptr,
                nullptr, nullptr, u, 512, skipraw, CH, NN, 128, nullptr);
        }
        // g = softmax-weighted neighbor sums of h, aliased onto u
        attn_kernel<<<NN, 256, 0, stream>>>(hcur, u, u, rowstart, csr_src);
        // h_next = relu(bn(g @ Wvstack + skipraw + (deg>0)*bvbar))  (626 blocks)
        gemm_fp32<32, 64, 2, 4, 4, 32><<<dim3(313, 2), 256, 0, stream>>>(
            u, 512, Wcomb, CH, nullptr, bvbar, deg, skipraw,
            bnS + l * 128, bnB + l * 128, dest, CH, nullptr, CH, NN, 512,
            (l == 2) ? keysG : nullptr);
        hcur = dest;
    }
    radix_pool_kernel<<<8, 256, 0, stream>>>(keysG, age, sel, zbuf);
    gather_kernel<<<240, 128, 0, stream>>>(h3, x, Wskip, bskip,
                                           bnS, bnB, sel, zbuf);
    mlp1_kernel<<<128, 256, 0, stream>>>(zbuf, W1, zh);
    mlp2_kernel<<<8, 256, 0, stream>>>(zh, b1, W2, b2, (float*)d_out);
}